// Round 4
// baseline (583.709 us; speedup 1.0000x reference)
//
#include <hip/hip_runtime.h>
#include <hip/hip_bf16.h>

typedef unsigned short ushort_t;
typedef __attribute__((ext_vector_type(8))) short short8;
typedef __attribute__((ext_vector_type(4))) float f32x4;

#define DI __device__ __forceinline__

DI float b2f(unsigned int u16) {
  union { unsigned int i; float f; } v;
  v.i = u16 << 16;
  return v.f;
}
DI ushort_t f2b(float f) {
  union { float f; unsigned int u; } v; v.f = f;
  unsigned int r = v.u + 0x7FFFu + ((v.u >> 16) & 1u);
  return (ushort_t)(r >> 16);
}

// ---------------------------------------------------------------------------
// Weight fp32 -> bf16 conversion (4 matrices in one grid-stride kernel)
// ---------------------------------------------------------------------------
__global__ void wcvt_kernel(const float* __restrict__ w0, const float* __restrict__ w1,
                            const float* __restrict__ w2, const float* __restrict__ w3,
                            ushort_t* __restrict__ o0, ushort_t* __restrict__ o1,
                            ushort_t* __restrict__ o2, ushort_t* __restrict__ o3) {
  const int n1 = 2304 * 768, n3 = 768 * 768;
  const int total = 2 * n1 + 2 * n3;
  for (int i = blockIdx.x * blockDim.x + threadIdx.x; i < total; i += gridDim.x * blockDim.x) {
    if (i < n1) o0[i] = f2b(w0[i]);
    else if (i < 2 * n1) o1[i - n1] = f2b(w1[i - n1]);
    else if (i < 2 * n1 + n3) o2[i - 2 * n1] = f2b(w2[i - 2 * n1]);
    else o3[i - 2 * n1 - n3] = f2b(w3[i - 2 * n1 - n3]);
  }
}

// ---------------------------------------------------------------------------
// GroupNorm stats, two-phase (parallel partials + tiny finalize)
// ---------------------------------------------------------------------------
__global__ void gn_partial_kernel(const float* __restrict__ video,
                                  const float* __restrict__ audio,
                                  float* __restrict__ part) {
  const int bid = blockIdx.x;
  const int tid = threadIdx.x;
  float s = 0.f, ss = 0.f;
  if (bid < 2048) {
    int bg = bid >> 4, f = bid & 15;
    int b = bg >> 5, g = bg & 31;
    const float* base = video + ((size_t)((b * 16 + f) * 768 + g * 24)) * 256 + tid;
#pragma unroll
    for (int cl = 0; cl < 24; ++cl) {
      float v = base[cl * 256];
      s += v; ss += v * v;
    }
  } else {
    int a = bid - 2048;
    int bg = a >> 2, p = a & 3;
    int b = bg >> 5, g = bg & 31;
    const float* base = audio + ((size_t)(b * 768 + g * 24)) * 1024 + p * 256 + tid;
#pragma unroll
    for (int cl = 0; cl < 24; ++cl) {
      float v = base[cl * 1024];
      s += v; ss += v * v;
    }
  }
  for (int off = 32; off > 0; off >>= 1) { s += __shfl_down(s, off, 64); ss += __shfl_down(ss, off, 64); }
  __shared__ float red[8];
  int wv = tid >> 6, ln = tid & 63;
  if (ln == 0) { red[wv * 2] = s; red[wv * 2 + 1] = ss; }
  __syncthreads();
  if (tid == 0) {
    part[bid * 2] = red[0] + red[2] + red[4] + red[6];
    part[bid * 2 + 1] = red[1] + red[3] + red[5] + red[7];
  }
}

__global__ void gn_final_kernel(const float* __restrict__ part,
                                float* __restrict__ mu, float* __restrict__ rs) {
  const int tid = threadIdx.x;  // 0..255
  float s = 0.f, ss = 0.f;
  if (tid < 128) {
#pragma unroll
    for (int i = 0; i < 16; ++i) { s += part[(tid * 16 + i) * 2]; ss += part[(tid * 16 + i) * 2 + 1]; }
    const float N = 24.f * 4096.f;
    float m = s / N;
    mu[tid] = m;
    rs[tid] = rsqrtf(ss / N - m * m + 1e-5f);
  } else {
    int a = tid - 128;
#pragma unroll
    for (int i = 0; i < 4; ++i) { s += part[(2048 + a * 4 + i) * 2]; ss += part[(2048 + a * 4 + i) * 2 + 1]; }
    const float N = 24.f * 1024.f;
    float m = s / N;
    mu[tid] = m;
    rs[tid] = rsqrtf(ss / N - m * m + 1e-5f);
  }
}

// ---------------------------------------------------------------------------
// Normalize video -> token-major bf16  Xv[n][c], n = b*4096 + f*256 + hw
// ---------------------------------------------------------------------------
__global__ void norm_video_kernel(const float* __restrict__ video,
                                  const float* __restrict__ mu, const float* __restrict__ rs,
                                  const float* __restrict__ sc, const float* __restrict__ bi,
                                  ushort_t* __restrict__ Xv) {
  __shared__ float T[32][257];
  const int bx = blockIdx.x;
  const int bf = bx / 24, ct = bx % 24;
  const int b = bf >> 4, f = bf & 15;
  const int c0 = ct * 32;
  const int tid = threadIdx.x;
  for (int i = 0; i < 32; ++i) {
    int c = c0 + i;
    int g = c / 24;
    float m = mu[b * 32 + g], r = rs[b * 32 + g];
    float v = video[((size_t)((b * 16 + f) * 768 + c)) * 256 + tid];
    T[i][tid] = (v - m) * r * sc[c] + bi[c];
  }
  __syncthreads();
  for (int i = 0; i < 32; ++i) {
    int id = i * 256 + tid;
    int c = id & 31, hw = id >> 5;
    Xv[((size_t)(b * 4096 + f * 256 + hw)) * 768 + c0 + c] = f2b(T[c][hw]);
  }
}

// Normalize audio -> token-major bf16  Xa[n][c], n = b*1024 + t
__global__ void norm_audio_kernel(const float* __restrict__ audio,
                                  const float* __restrict__ mu, const float* __restrict__ rs,
                                  const float* __restrict__ sc, const float* __restrict__ bi,
                                  ushort_t* __restrict__ Xa) {
  __shared__ float T[32][257];
  const int bx = blockIdx.x;
  const int bt = bx / 24, ct = bx % 24;
  const int b = bt >> 2, t0 = (bt & 3) * 256;
  const int c0 = ct * 32;
  const int tid = threadIdx.x;
  for (int i = 0; i < 32; ++i) {
    int c = c0 + i;
    int g = c / 24;
    float m = mu[128 + b * 32 + g], r = rs[128 + b * 32 + g];
    float v = audio[((size_t)(b * 768 + c)) * 1024 + t0 + tid];
    T[i][tid] = (v - m) * r * sc[c] + bi[c];
  }
  __syncthreads();
  for (int i = 0; i < 32; ++i) {
    int id = i * 256 + tid;
    int c = id & 31, tt = id >> 5;
    Xa[((size_t)(b * 1024 + t0 + tt)) * 768 + c0 + c] = f2b(T[c][tt]);
  }
}

// ---------------------------------------------------------------------------
// MFMA GEMM:  D[token m][o n] = sum_c A[m][c] * W[n][c]
// MODE 0: QKV epilogue; MODE 1: video proj; MODE 2: audio proj (residual add)
// ---------------------------------------------------------------------------
template <int MODE>
__global__ __launch_bounds__(256) void gemm_kernel(
    const ushort_t* __restrict__ A, const ushort_t* __restrict__ W,
    const float* __restrict__ bias,
    void* __restrict__ p0, void* __restrict__ p1, void* __restrict__ p2,
    int M) {
  __shared__ ushort_t sm[18432];
  ushort_t* sA = sm;
  ushort_t* sB = sm + 9216;
  const int tid = threadIdx.x;
  const int lane = tid & 63, wave = tid >> 6;
  const int quad = lane >> 4, l16 = lane & 15;
  const int n0 = blockIdx.x * 128, m0 = blockIdx.y * 128;
  const int wm = (wave & 1) * 64, wn = (wave >> 1) * 64;

  f32x4 acc[4][4];
#pragma unroll
  for (int i = 0; i < 4; ++i)
#pragma unroll
    for (int j = 0; j < 4; ++j) acc[i][j] = (f32x4){0.f, 0.f, 0.f, 0.f};

  for (int kc = 0; kc < 768; kc += 64) {
#pragma unroll
    for (int i = 0; i < 4; ++i) {
      int cid = i * 256 + tid;
      int row = cid >> 3, ch = cid & 7;
      *reinterpret_cast<uint4*>(sA + row * 72 + ch * 8) =
          *reinterpret_cast<const uint4*>(A + (size_t)(m0 + row) * 768 + kc + ch * 8);
      *reinterpret_cast<uint4*>(sB + row * 72 + ch * 8) =
          *reinterpret_cast<const uint4*>(W + (size_t)(n0 + row) * 768 + kc + ch * 8);
    }
    __syncthreads();
#pragma unroll
    for (int ks = 0; ks < 2; ++ks) {
      short8 av[4], bv[4];
#pragma unroll
      for (int im = 0; im < 4; ++im)
        av[im] = *reinterpret_cast<const short8*>(sA + (wm + im * 16 + l16) * 72 + ks * 32 + quad * 8);
#pragma unroll
      for (int in = 0; in < 4; ++in)
        bv[in] = *reinterpret_cast<const short8*>(sB + (wn + in * 16 + l16) * 72 + ks * 32 + quad * 8);
#pragma unroll
      for (int im = 0; im < 4; ++im)
#pragma unroll
        for (int in = 0; in < 4; ++in)
          acc[im][in] = __builtin_amdgcn_mfma_f32_16x16x32_bf16(av[im], bv[in], acc[im][in], 0, 0, 0);
    }
    __syncthreads();
  }

  ushort_t* sC = sm;  // epilogue scratch [128][136] bf16
  if (MODE == 0) {
    const int section = n0 / 768;  // 0=Q 1=K 2=V
    const int obase = n0 - section * 768;
    if (section < 2) {
#pragma unroll
      for (int in = 0; in < 4; ++in) {
        int ol = wn + in * 16 + l16;
        float bv_ = bias[n0 + ol];
#pragma unroll
        for (int im = 0; im < 4; ++im)
#pragma unroll
          for (int r = 0; r < 4; ++r) {
            int row = wm + im * 16 + quad * 4 + r;
            sC[row * 136 + ol] = f2b(acc[im][in][r] + bv_);
          }
      }
      __syncthreads();
      ushort_t* dst = (ushort_t*)(section == 0 ? p0 : p1);
#pragma unroll
      for (int i = 0; i < 8; ++i) {
        int cid = i * 256 + tid;
        int row = cid >> 4, ch = cid & 15;
        *reinterpret_cast<uint4*>(dst + (size_t)(m0 + row) * 768 + obase + ch * 8) =
            *reinterpret_cast<const uint4*>(sC + row * 136 + ch * 8);
      }
    } else {
#pragma unroll
      for (int in = 0; in < 4; ++in) {
        int ol = wn + in * 16 + l16;
        float bv_ = bias[n0 + ol];
#pragma unroll
        for (int im = 0; im < 4; ++im)
#pragma unroll
          for (int r = 0; r < 4; ++r) {
            int mr = wm + im * 16 + quad * 4 + r;
            sC[ol * 136 + mr] = f2b(acc[im][in][r] + bv_);
          }
      }
      __syncthreads();
      ushort_t* dst = (ushort_t*)p2;
#pragma unroll
      for (int i = 0; i < 8; ++i) {
        int cid = i * 256 + tid;
        int o = cid >> 4, ch = cid & 15;
        *reinterpret_cast<uint4*>(dst + (size_t)(obase + o) * M + m0 + ch * 8) =
            *reinterpret_cast<const uint4*>(sC + o * 136 + ch * 8);
      }
    }
  } else {
#pragma unroll
    for (int in = 0; in < 4; ++in) {
      int ol = wn + in * 16 + l16;
      float bv_ = bias[n0 + ol];
#pragma unroll
      for (int im = 0; im < 4; ++im)
#pragma unroll
        for (int r = 0; r < 4; ++r) {
          int mr = wm + im * 16 + quad * 4 + r;
          sC[ol * 136 + mr] = f2b(acc[im][in][r] + bv_);
        }
    }
    __syncthreads();
    float* outp = (float*)p0;
    const float* resp = (const float*)p1;
#pragma unroll
    for (int i = 0; i < 16; ++i) {
      int cid = i * 256 + tid;
      int o = cid >> 5, ch = cid & 31;
      uint2 pk = *reinterpret_cast<const uint2*>(sC + o * 136 + ch * 4);
      size_t gidx;
      if (MODE == 1) {
        int b = m0 >> 12, f = (m0 >> 8) & 15, hw0 = m0 & 255;
        gidx = ((size_t)((b * 16 + f) * 768 + n0 + o)) * 256 + hw0 + ch * 4;
      } else {
        int b = m0 >> 10, t0 = m0 & 1023;
        gidx = ((size_t)(b * 768 + n0 + o)) * 1024 + t0 + ch * 4;
      }
      float4 rv = *reinterpret_cast<const float4*>(resp + gidx);
      float4 ov;
      ov.x = rv.x + b2f(pk.x & 0xffff);
      ov.y = rv.y + b2f(pk.x >> 16);
      ov.z = rv.z + b2f(pk.y & 0xffff);
      ov.w = rv.w + b2f(pk.y >> 16);
      *reinterpret_cast<float4*>(outp + gidx) = ov;
    }
  }
}

// ---------------------------------------------------------------------------
// MFMA flash attention v2: barrier-free.
// All MFMA A/B fragments are 16B-contiguous -> loaded DIRECTLY from global
// (L2-hot; each 16-lane row group covers one full 64B cacheline). Only P
// round-trips through a WAVE-PRIVATE LDS region (C->A layout transform), so
// the kernel contains zero __syncthreads. Wave owns 16 q rows; block = 4
// waves = 64 q. s-tiles of 128. Softmax scale (ch^-0.5 = 0.125) folded into
// the fp32 softmax (q*scale, k*scale in ref => 0.125 * S).
// ---------------------------------------------------------------------------
template <int QW, int SW>
__global__ __launch_bounds__(256) void attn_mfma2_kernel(
    const ushort_t* __restrict__ Qt, const ushort_t* __restrict__ Kt,
    const ushort_t* __restrict__ Vc, ushort_t* __restrict__ Ot,
    int TQb, int TSb, int Ms) {
  __shared__ ushort_t sP[4 * 16 * 136];  // wave-private 16x136 regions
  const int tid = threadIdx.x;
  const int lane = tid & 63, wave = tid >> 6;
  const int quad = lane >> 4, l16 = lane & 15;
  const int NQT = QW / 64;
  const int bx = blockIdx.x;
  const int qt = bx % NQT;
  const int win = (bx / NQT) & 3;
  const int h = (bx / (NQT * 4)) % 12;
  const int b = bx / (NQT * 48);
  const int hc = h * 64;
  const int nq0 = b * TQb + win * QW + qt * 64 + wave * 16;  // wave's q base
  const int ns_base = b * TSb + win * SW;
  ushort_t* sPw = sP + wave * 16 * 136;

  // Q A-frags direct from global (row = l16, k = ks*32 + quad*8 + j)
  const ushort_t* qbase = Qt + (size_t)(nq0 + l16) * 768 + hc + quad * 8;
  short8 qf0 = *reinterpret_cast<const short8*>(qbase);
  short8 qf1 = *reinterpret_cast<const short8*>(qbase + 32);

  float mr[4], lr[4];
  f32x4 on[4];
#pragma unroll
  for (int r = 0; r < 4; ++r) { mr[r] = -1e30f; lr[r] = 0.f; }
#pragma unroll
  for (int nc = 0; nc < 4; ++nc) on[nc] = (f32x4){0.f, 0.f, 0.f, 0.f};

  const ushort_t* kb0 = Kt + (size_t)(ns_base + l16) * 768 + hc + quad * 8;
  const ushort_t* vb0 = Vc + (size_t)(hc + l16) * Ms + ns_base + quad * 8;

  for (int t = 0; t < SW / 128; ++t) {
    const ushort_t* kb = kb0 + (size_t)t * 128 * 768;
    // ---- S = Q K^T : K B-frags direct from global (row = s, k = ch)
    f32x4 sf[8];
#pragma unroll
    for (int nt = 0; nt < 8; ++nt) sf[nt] = (f32x4){0.f, 0.f, 0.f, 0.f};
#pragma unroll
    for (int nt = 0; nt < 8; ++nt) {
      short8 kfa = *reinterpret_cast<const short8*>(kb + (size_t)nt * 16 * 768);
      short8 kfb = *reinterpret_cast<const short8*>(kb + (size_t)nt * 16 * 768 + 32);
      sf[nt] = __builtin_amdgcn_mfma_f32_16x16x32_bf16(qf0, kfa, sf[nt], 0, 0, 0);
      sf[nt] = __builtin_amdgcn_mfma_f32_16x16x32_bf16(qf1, kfb, sf[nt], 0, 0, 0);
    }
    // ---- V B-frags direct from global (row = ch, k = s), issue before softmax
    short8 vf[4][4];
#pragma unroll
    for (int ks = 0; ks < 4; ++ks)
#pragma unroll
      for (int nc = 0; nc < 4; ++nc)
        vf[ks][nc] = *reinterpret_cast<const short8*>(
            vb0 + (size_t)(nc * 16) * Ms + t * 128 + ks * 32);
    // ---- online softmax in registers; rows (q = quad*4 + r) are wave-local,
    // cols spread over l16 (xor 1/2/4/8 stays in the 16-lane group)
#pragma unroll
    for (int r = 0; r < 4; ++r) {
      float m_ = -1e30f;
#pragma unroll
      for (int nt = 0; nt < 8; ++nt) {
        float v = sf[nt][r] * 0.125f;
        sf[nt][r] = v;
        m_ = fmaxf(m_, v);
      }
#pragma unroll
      for (int off = 1; off < 16; off <<= 1) m_ = fmaxf(m_, __shfl_xor(m_, off));
      float mnew = fmaxf(mr[r], m_);
      float al = __expf(mr[r] - mnew);
      float ls = 0.f;
      int prow = (quad * 4 + r) * 136;
#pragma unroll
      for (int nt = 0; nt < 8; ++nt) {
        float p = __expf(sf[nt][r] - mnew);
        ls += p;
        sPw[prow + nt * 16 + l16] = f2b(p);
      }
#pragma unroll
      for (int off = 1; off < 16; off <<= 1) ls += __shfl_xor(ls, off);
      lr[r] = lr[r] * al + ls;
      mr[r] = mnew;
#pragma unroll
      for (int nc = 0; nc < 4; ++nc) on[nc][r] *= al;
    }
    // ---- O += P V : P A-frags from wave-private LDS (compiler inserts
    // lgkmcnt wait; no barrier needed)
#pragma unroll
    for (int ks = 0; ks < 4; ++ks) {
      short8 pf = *reinterpret_cast<const short8*>(sPw + l16 * 136 + ks * 32 + quad * 8);
#pragma unroll
      for (int nc = 0; nc < 4; ++nc)
        on[nc] = __builtin_amdgcn_mfma_f32_16x16x32_bf16(pf, vf[ks][nc], on[nc], 0, 0, 0);
    }
  }
  // ---- finalize: normalize, bounce through wave-private sP for coalesced out
#pragma unroll
  for (int r = 0; r < 4; ++r) {
    float inv = 1.f / lr[r];
    int prow = (quad * 4 + r) * 136;
#pragma unroll
    for (int nc = 0; nc < 4; ++nc)
      sPw[prow + nc * 16 + l16] = f2b(on[nc][r] * inv);
  }
  int row = lane >> 2, cpart = (lane & 3) * 16;
  uint4 o0 = *reinterpret_cast<const uint4*>(sPw + row * 136 + cpart);
  uint4 o1 = *reinterpret_cast<const uint4*>(sPw + row * 136 + cpart + 8);
  ushort_t* obase = Ot + (size_t)(nq0 + row) * 768 + hc + cpart;
  *reinterpret_cast<uint4*>(obase) = o0;
  *reinterpret_cast<uint4*>(obase + 8) = o1;
}

// ---------------------------------------------------------------------------
extern "C" void kernel_launch(void* const* d_in, const int* in_sizes, int n_in,
                              void* d_out, int out_size, void* d_ws, size_t ws_size,
                              hipStream_t stream) {
  (void)in_sizes; (void)n_in; (void)out_size; (void)ws_size;
  const float* video = (const float*)d_in[0];
  const float* audio = (const float*)d_in[1];
  const float* vn_s = (const float*)d_in[2];
  const float* vn_b = (const float*)d_in[3];
  const float* an_s = (const float*)d_in[4];
  const float* an_b = (const float*)d_in[5];
  const float* vqkv_w = (const float*)d_in[6];
  const float* vqkv_b = (const float*)d_in[7];
  const float* aqkv_w = (const float*)d_in[8];
  const float* aqkv_b = (const float*)d_in[9];
  const float* vproj_w = (const float*)d_in[10];
  const float* vproj_b = (const float*)d_in[11];
  const float* aproj_w = (const float*)d_in[12];
  const float* aproj_b = (const float*)d_in[13];

  float* out_v = (float*)d_out;
  float* out_a = out_v + (size_t)4 * 16 * 768 * 16 * 16;

  char* ws = (char*)d_ws;
  size_t off = 0;
  auto carve = [&](size_t bytes) {
    char* p = ws + off;
    off += (bytes + 255) & ~(size_t)255;
    return p;
  };
  float* mu = (float*)carve(256 * 4);
  float* rs = (float*)carve(256 * 4);
  float* part = (float*)carve(2560 * 2 * 4);
  ushort_t* Xv = (ushort_t*)carve((size_t)16384 * 768 * 2);
  ushort_t* Xa = (ushort_t*)carve((size_t)4096 * 768 * 2);
  ushort_t* Wqv = (ushort_t*)carve((size_t)2304 * 768 * 2);
  ushort_t* Wqa = (ushort_t*)carve((size_t)2304 * 768 * 2);
  ushort_t* Wpv = (ushort_t*)carve((size_t)768 * 768 * 2);
  ushort_t* Wpa = (ushort_t*)carve((size_t)768 * 768 * 2);
  ushort_t* Qv = (ushort_t*)carve((size_t)16384 * 768 * 2);
  ushort_t* Kv = (ushort_t*)carve((size_t)16384 * 768 * 2);
  ushort_t* Vv = (ushort_t*)carve((size_t)16384 * 768 * 2);
  ushort_t* Qa = (ushort_t*)carve((size_t)4096 * 768 * 2);
  ushort_t* Ka = (ushort_t*)carve((size_t)4096 * 768 * 2);
  ushort_t* Va = (ushort_t*)carve((size_t)4096 * 768 * 2);
  ushort_t* Ov = Xv;  // alias: X no longer needed after QKV GEMM
  ushort_t* Oa = Xa;

  wcvt_kernel<<<1024, 256, 0, stream>>>(vqkv_w, aqkv_w, vproj_w, aproj_w, Wqv, Wqa, Wpv, Wpa);
  gn_partial_kernel<<<2560, 256, 0, stream>>>(video, audio, part);
  gn_final_kernel<<<1, 256, 0, stream>>>(part, mu, rs);
  norm_video_kernel<<<1536, 256, 0, stream>>>(video, mu, rs, vn_s, vn_b, Xv);
  norm_audio_kernel<<<384, 256, 0, stream>>>(audio, mu, rs, an_s, an_b, Xa);
  gemm_kernel<0><<<dim3(18, 128), 256, 0, stream>>>(Xv, Wqv, vqkv_b, Qv, Kv, Vv, 16384);
  gemm_kernel<0><<<dim3(18, 32), 256, 0, stream>>>(Xa, Wqa, aqkv_b, Qa, Ka, Va, 4096);
  // video queries attend audio windows: QW=1024, SW=256
  attn_mfma2_kernel<1024, 256><<<3072, 256, 0, stream>>>(Qv, Ka, Va, Ov, 4096, 1024, 4096);
  // audio queries attend video windows: QW=256, SW=1024
  attn_mfma2_kernel<256, 1024><<<768, 256, 0, stream>>>(Qa, Kv, Vv, Oa, 1024, 4096, 16384);
  gemm_kernel<1><<<dim3(6, 128), 256, 0, stream>>>(Ov, Wpv, vproj_b, (void*)out_v, (void*)video, nullptr, 16384);
  gemm_kernel<2><<<dim3(6, 32), 256, 0, stream>>>(Oa, Wpa, aproj_b, (void*)out_a, (void*)audio, nullptr, 4096);
}

// Round 5
// 483.114 us; speedup vs baseline: 1.2082x; 1.2082x over previous
//
#include <hip/hip_runtime.h>
#include <hip/hip_bf16.h>

typedef unsigned short ushort_t;
typedef __attribute__((ext_vector_type(8))) short short8;
typedef __attribute__((ext_vector_type(4))) float f32x4;

#define DI __device__ __forceinline__

DI float b2f(unsigned int u16) {
  union { unsigned int i; float f; } v;
  v.i = u16 << 16;
  return v.f;
}
DI ushort_t f2b(float f) {
  union { float f; unsigned int u; } v; v.f = f;
  unsigned int r = v.u + 0x7FFFu + ((v.u >> 16) & 1u);
  return (ushort_t)(r >> 16);
}

// ---------------------------------------------------------------------------
// Weight fp32 -> bf16 conversion (4 matrices in one grid-stride kernel)
// ---------------------------------------------------------------------------
__global__ void wcvt_kernel(const float* __restrict__ w0, const float* __restrict__ w1,
                            const float* __restrict__ w2, const float* __restrict__ w3,
                            ushort_t* __restrict__ o0, ushort_t* __restrict__ o1,
                            ushort_t* __restrict__ o2, ushort_t* __restrict__ o3) {
  const int n1 = 2304 * 768, n3 = 768 * 768;
  const int total = 2 * n1 + 2 * n3;
  for (int i = blockIdx.x * blockDim.x + threadIdx.x; i < total; i += gridDim.x * blockDim.x) {
    if (i < n1) o0[i] = f2b(w0[i]);
    else if (i < 2 * n1) o1[i - n1] = f2b(w1[i - n1]);
    else if (i < 2 * n1 + n3) o2[i - 2 * n1] = f2b(w2[i - 2 * n1]);
    else o3[i - 2 * n1 - n3] = f2b(w3[i - 2 * n1 - n3]);
  }
}

// ---------------------------------------------------------------------------
// GroupNorm stats, two-phase (parallel partials + tiny finalize)
// ---------------------------------------------------------------------------
__global__ void gn_partial_kernel(const float* __restrict__ video,
                                  const float* __restrict__ audio,
                                  float* __restrict__ part) {
  const int bid = blockIdx.x;
  const int tid = threadIdx.x;
  float s = 0.f, ss = 0.f;
  if (bid < 2048) {
    int bg = bid >> 4, f = bid & 15;
    int b = bg >> 5, g = bg & 31;
    const float* base = video + ((size_t)((b * 16 + f) * 768 + g * 24)) * 256 + tid;
#pragma unroll
    for (int cl = 0; cl < 24; ++cl) {
      float v = base[cl * 256];
      s += v; ss += v * v;
    }
  } else {
    int a = bid - 2048;
    int bg = a >> 2, p = a & 3;
    int b = bg >> 5, g = bg & 31;
    const float* base = audio + ((size_t)(b * 768 + g * 24)) * 1024 + p * 256 + tid;
#pragma unroll
    for (int cl = 0; cl < 24; ++cl) {
      float v = base[cl * 1024];
      s += v; ss += v * v;
    }
  }
  for (int off = 32; off > 0; off >>= 1) { s += __shfl_down(s, off, 64); ss += __shfl_down(ss, off, 64); }
  __shared__ float red[8];
  int wv = tid >> 6, ln = tid & 63;
  if (ln == 0) { red[wv * 2] = s; red[wv * 2 + 1] = ss; }
  __syncthreads();
  if (tid == 0) {
    part[bid * 2] = red[0] + red[2] + red[4] + red[6];
    part[bid * 2 + 1] = red[1] + red[3] + red[5] + red[7];
  }
}

__global__ void gn_final_kernel(const float* __restrict__ part,
                                float* __restrict__ mu, float* __restrict__ rs) {
  const int tid = threadIdx.x;  // 0..255
  float s = 0.f, ss = 0.f;
  if (tid < 128) {
#pragma unroll
    for (int i = 0; i < 16; ++i) { s += part[(tid * 16 + i) * 2]; ss += part[(tid * 16 + i) * 2 + 1]; }
    const float N = 24.f * 4096.f;
    float m = s / N;
    mu[tid] = m;
    rs[tid] = rsqrtf(ss / N - m * m + 1e-5f);
  } else {
    int a = tid - 128;
#pragma unroll
    for (int i = 0; i < 4; ++i) { s += part[(2048 + a * 4 + i) * 2]; ss += part[(2048 + a * 4 + i) * 2 + 1]; }
    const float N = 24.f * 1024.f;
    float m = s / N;
    mu[tid] = m;
    rs[tid] = rsqrtf(ss / N - m * m + 1e-5f);
  }
}

// ---------------------------------------------------------------------------
// Normalize video -> token-major bf16  Xv[n][c], n = b*4096 + f*256 + hw
// ---------------------------------------------------------------------------
__global__ void norm_video_kernel(const float* __restrict__ video,
                                  const float* __restrict__ mu, const float* __restrict__ rs,
                                  const float* __restrict__ sc, const float* __restrict__ bi,
                                  ushort_t* __restrict__ Xv) {
  __shared__ float T[32][257];
  const int bx = blockIdx.x;
  const int bf = bx / 24, ct = bx % 24;
  const int b = bf >> 4, f = bf & 15;
  const int c0 = ct * 32;
  const int tid = threadIdx.x;
  for (int i = 0; i < 32; ++i) {
    int c = c0 + i;
    int g = c / 24;
    float m = mu[b * 32 + g], r = rs[b * 32 + g];
    float v = video[((size_t)((b * 16 + f) * 768 + c)) * 256 + tid];
    T[i][tid] = (v - m) * r * sc[c] + bi[c];
  }
  __syncthreads();
  for (int i = 0; i < 32; ++i) {
    int id = i * 256 + tid;
    int c = id & 31, hw = id >> 5;
    Xv[((size_t)(b * 4096 + f * 256 + hw)) * 768 + c0 + c] = f2b(T[c][hw]);
  }
}

// Normalize audio -> token-major bf16  Xa[n][c], n = b*1024 + t
__global__ void norm_audio_kernel(const float* __restrict__ audio,
                                  const float* __restrict__ mu, const float* __restrict__ rs,
                                  const float* __restrict__ sc, const float* __restrict__ bi,
                                  ushort_t* __restrict__ Xa) {
  __shared__ float T[32][257];
  const int bx = blockIdx.x;
  const int bt = bx / 24, ct = bx % 24;
  const int b = bt >> 2, t0 = (bt & 3) * 256;
  const int c0 = ct * 32;
  const int tid = threadIdx.x;
  for (int i = 0; i < 32; ++i) {
    int c = c0 + i;
    int g = c / 24;
    float m = mu[128 + b * 32 + g], r = rs[128 + b * 32 + g];
    float v = audio[((size_t)(b * 768 + c)) * 1024 + t0 + tid];
    T[i][tid] = (v - m) * r * sc[c] + bi[c];
  }
  __syncthreads();
  for (int i = 0; i < 32; ++i) {
    int id = i * 256 + tid;
    int c = id & 31, tt = id >> 5;
    Xa[((size_t)(b * 1024 + t0 + tt)) * 768 + c0 + c] = f2b(T[c][tt]);
  }
}

// ---------------------------------------------------------------------------
// MFMA GEMM:  D[token m][o n] = sum_c A[m][c] * W[n][c]
// MODE 0: QKV epilogue; MODE 1: video proj; MODE 2: audio proj (residual add)
// ---------------------------------------------------------------------------
template <int MODE>
__global__ __launch_bounds__(256) void gemm_kernel(
    const ushort_t* __restrict__ A, const ushort_t* __restrict__ W,
    const float* __restrict__ bias,
    void* __restrict__ p0, void* __restrict__ p1, void* __restrict__ p2,
    int M) {
  __shared__ ushort_t sm[18432];
  ushort_t* sA = sm;
  ushort_t* sB = sm + 9216;
  const int tid = threadIdx.x;
  const int lane = tid & 63, wave = tid >> 6;
  const int quad = lane >> 4, l16 = lane & 15;
  const int n0 = blockIdx.x * 128, m0 = blockIdx.y * 128;
  const int wm = (wave & 1) * 64, wn = (wave >> 1) * 64;

  f32x4 acc[4][4];
#pragma unroll
  for (int i = 0; i < 4; ++i)
#pragma unroll
    for (int j = 0; j < 4; ++j) acc[i][j] = (f32x4){0.f, 0.f, 0.f, 0.f};

  for (int kc = 0; kc < 768; kc += 64) {
#pragma unroll
    for (int i = 0; i < 4; ++i) {
      int cid = i * 256 + tid;
      int row = cid >> 3, ch = cid & 7;
      *reinterpret_cast<uint4*>(sA + row * 72 + ch * 8) =
          *reinterpret_cast<const uint4*>(A + (size_t)(m0 + row) * 768 + kc + ch * 8);
      *reinterpret_cast<uint4*>(sB + row * 72 + ch * 8) =
          *reinterpret_cast<const uint4*>(W + (size_t)(n0 + row) * 768 + kc + ch * 8);
    }
    __syncthreads();
#pragma unroll
    for (int ks = 0; ks < 2; ++ks) {
      short8 av[4], bv[4];
#pragma unroll
      for (int im = 0; im < 4; ++im)
        av[im] = *reinterpret_cast<const short8*>(sA + (wm + im * 16 + l16) * 72 + ks * 32 + quad * 8);
#pragma unroll
      for (int in = 0; in < 4; ++in)
        bv[in] = *reinterpret_cast<const short8*>(sB + (wn + in * 16 + l16) * 72 + ks * 32 + quad * 8);
#pragma unroll
      for (int im = 0; im < 4; ++im)
#pragma unroll
        for (int in = 0; in < 4; ++in)
          acc[im][in] = __builtin_amdgcn_mfma_f32_16x16x32_bf16(av[im], bv[in], acc[im][in], 0, 0, 0);
    }
    __syncthreads();
  }

  ushort_t* sC = sm;  // epilogue scratch [128][136] bf16
  if (MODE == 0) {
    const int section = n0 / 768;  // 0=Q 1=K 2=V
    const int obase = n0 - section * 768;
    if (section < 2) {
#pragma unroll
      for (int in = 0; in < 4; ++in) {
        int ol = wn + in * 16 + l16;
        float bv_ = bias[n0 + ol];
#pragma unroll
        for (int im = 0; im < 4; ++im)
#pragma unroll
          for (int r = 0; r < 4; ++r) {
            int row = wm + im * 16 + quad * 4 + r;
            sC[row * 136 + ol] = f2b(acc[im][in][r] + bv_);
          }
      }
      __syncthreads();
      ushort_t* dst = (ushort_t*)(section == 0 ? p0 : p1);
#pragma unroll
      for (int i = 0; i < 8; ++i) {
        int cid = i * 256 + tid;
        int row = cid >> 4, ch = cid & 15;
        *reinterpret_cast<uint4*>(dst + (size_t)(m0 + row) * 768 + obase + ch * 8) =
            *reinterpret_cast<const uint4*>(sC + row * 136 + ch * 8);
      }
    } else {
#pragma unroll
      for (int in = 0; in < 4; ++in) {
        int ol = wn + in * 16 + l16;
        float bv_ = bias[n0 + ol];
#pragma unroll
        for (int im = 0; im < 4; ++im)
#pragma unroll
          for (int r = 0; r < 4; ++r) {
            int mr = wm + im * 16 + quad * 4 + r;
            sC[ol * 136 + mr] = f2b(acc[im][in][r] + bv_);
          }
      }
      __syncthreads();
      ushort_t* dst = (ushort_t*)p2;
#pragma unroll
      for (int i = 0; i < 8; ++i) {
        int cid = i * 256 + tid;
        int o = cid >> 4, ch = cid & 15;
        *reinterpret_cast<uint4*>(dst + (size_t)(obase + o) * M + m0 + ch * 8) =
            *reinterpret_cast<const uint4*>(sC + o * 136 + ch * 8);
      }
    }
  } else {
#pragma unroll
    for (int in = 0; in < 4; ++in) {
      int ol = wn + in * 16 + l16;
      float bv_ = bias[n0 + ol];
#pragma unroll
      for (int im = 0; im < 4; ++im)
#pragma unroll
        for (int r = 0; r < 4; ++r) {
          int mr = wm + im * 16 + quad * 4 + r;
          sC[ol * 136 + mr] = f2b(acc[im][in][r] + bv_);
        }
    }
    __syncthreads();
    float* outp = (float*)p0;
    const float* resp = (const float*)p1;
#pragma unroll
    for (int i = 0; i < 16; ++i) {
      int cid = i * 256 + tid;
      int o = cid >> 5, ch = cid & 31;
      uint2 pk = *reinterpret_cast<const uint2*>(sC + o * 136 + ch * 4);
      size_t gidx;
      if (MODE == 1) {
        int b = m0 >> 12, f = (m0 >> 8) & 15, hw0 = m0 & 255;
        gidx = ((size_t)((b * 16 + f) * 768 + n0 + o)) * 256 + hw0 + ch * 4;
      } else {
        int b = m0 >> 10, t0 = m0 & 1023;
        gidx = ((size_t)(b * 768 + n0 + o)) * 1024 + t0 + ch * 4;
      }
      float4 rv = *reinterpret_cast<const float4*>(resp + gidx);
      float4 ov;
      ov.x = rv.x + b2f(pk.x & 0xffff);
      ov.y = rv.y + b2f(pk.x >> 16);
      ov.z = rv.z + b2f(pk.y & 0xffff);
      ov.w = rv.w + b2f(pk.y >> 16);
      *reinterpret_cast<float4*>(outp + gidx) = ov;
    }
  }
}

// ---------------------------------------------------------------------------
// MFMA flash attention v3 (LDS-staged, amortized).
// 128 q per block (4 waves; wave owns 2 subtiles of 16 q), s-tiles of 128.
// LDS: K [128][72] (also Q staging) + V [64][136] + wave-private P [16][136]
// = 53.2 KB -> 3 blocks/CU (R3's 58.4 KB gave only 2). 2 barriers per s-tile
// (K+V staged together). K-frag ds_reads shared across both q-subtiles.
// Q A-frags in registers; softmax state in registers (rows wave-local,
// shfl_xor 1/2/4/8 within the 16-lane column group); scale 0.125 applied in
// fp32 on S (q*scale, k*scale in ref == 0.125*S).
// ---------------------------------------------------------------------------
template <int QW, int SW>
__global__ __launch_bounds__(256) void attn_mfma3_kernel(
    const ushort_t* __restrict__ Qt, const ushort_t* __restrict__ Kt,
    const ushort_t* __restrict__ Vc, ushort_t* __restrict__ Ot,
    int TQb, int TSb, int Ms) {
  __shared__ ushort_t sK[128 * 72];      // K tile (stride 72); Q staging at start
  __shared__ ushort_t sV[64 * 136];      // V tile [ch][s] (stride 136)
  __shared__ ushort_t sP[4][16 * 136];   // wave-private P / O bounce
  const int tid = threadIdx.x;
  const int lane = tid & 63, wave = tid >> 6;
  const int quad = lane >> 4, l16 = lane & 15;
  const int NQT = QW / 128;
  const int bx = blockIdx.x;
  const int qt = bx % NQT;
  const int win = (bx / NQT) & 3;
  const int h = (bx / (NQT * 4)) % 12;
  const int b = bx / (NQT * 48);
  const int hc = h * 64;
  const int nq0 = b * TQb + win * QW + qt * 128;
  const int ns_base = b * TSb + win * SW;
  ushort_t* sPw = sP[wave];

  // ---- stage Q (128 x 64) into sK, pull A-frags for both subtiles
#pragma unroll
  for (int i = 0; i < 4; ++i) {
    int c = i * 256 + tid;
    int row = c >> 3, cc = c & 7;
    *reinterpret_cast<uint4*>(sK + row * 72 + cc * 8) =
        *reinterpret_cast<const uint4*>(Qt + (size_t)(nq0 + row) * 768 + hc + cc * 8);
  }
  __syncthreads();
  short8 qf[2][2];
#pragma unroll
  for (int sub = 0; sub < 2; ++sub)
#pragma unroll
    for (int ks = 0; ks < 2; ++ks)
      qf[sub][ks] = *reinterpret_cast<const short8*>(
          sK + (sub * 64 + wave * 16 + l16) * 72 + ks * 32 + quad * 8);

  float mr[2][4], lr[2][4];
  f32x4 on[2][4];
#pragma unroll
  for (int sub = 0; sub < 2; ++sub) {
#pragma unroll
    for (int r = 0; r < 4; ++r) { mr[sub][r] = -1e30f; lr[sub][r] = 0.f; }
#pragma unroll
    for (int nc = 0; nc < 4; ++nc) on[sub][nc] = (f32x4){0.f, 0.f, 0.f, 0.f};
  }

  for (int t = 0; t < SW / 128; ++t) {
    const int ns0 = ns_base + t * 128;
    __syncthreads();  // sK/sV free (Q frags pulled / previous tile finished)
    // ---- stage K [128 s][64 ch] and V [64 ch][128 s]
#pragma unroll
    for (int i = 0; i < 4; ++i) {
      int c = i * 256 + tid;
      int row = c >> 3, cc = c & 7;
      *reinterpret_cast<uint4*>(sK + row * 72 + cc * 8) =
          *reinterpret_cast<const uint4*>(Kt + (size_t)(ns0 + row) * 768 + hc + cc * 8);
    }
#pragma unroll
    for (int i = 0; i < 4; ++i) {
      int c = i * 256 + tid;
      int ch = c >> 4, cc = c & 15;
      *reinterpret_cast<uint4*>(sV + ch * 136 + cc * 8) =
          *reinterpret_cast<const uint4*>(Vc + (size_t)(hc + ch) * Ms + ns0 + cc * 8);
    }
    __syncthreads();
    // ---- S = Q K^T for both subtiles, sharing each K frag read
    f32x4 sf[2][8];
#pragma unroll
    for (int sub = 0; sub < 2; ++sub)
#pragma unroll
      for (int nt = 0; nt < 8; ++nt) sf[sub][nt] = (f32x4){0.f, 0.f, 0.f, 0.f};
#pragma unroll
    for (int ks = 0; ks < 2; ++ks) {
#pragma unroll
      for (int nt = 0; nt < 8; ++nt) {
        short8 kf = *reinterpret_cast<const short8*>(sK + (nt * 16 + l16) * 72 + ks * 32 + quad * 8);
        sf[0][nt] = __builtin_amdgcn_mfma_f32_16x16x32_bf16(qf[0][ks], kf, sf[0][nt], 0, 0, 0);
        sf[1][nt] = __builtin_amdgcn_mfma_f32_16x16x32_bf16(qf[1][ks], kf, sf[1][nt], 0, 0, 0);
      }
    }
    // ---- per subtile: online softmax -> P (wave-private LDS) -> PV
#pragma unroll
    for (int sub = 0; sub < 2; ++sub) {
#pragma unroll
      for (int r = 0; r < 4; ++r) {
        float m_ = -1e30f;
#pragma unroll
        for (int nt = 0; nt < 8; ++nt) {
          float v = sf[sub][nt][r] * 0.125f;
          sf[sub][nt][r] = v;
          m_ = fmaxf(m_, v);
        }
#pragma unroll
        for (int off = 1; off < 16; off <<= 1) m_ = fmaxf(m_, __shfl_xor(m_, off));
        float mnew = fmaxf(mr[sub][r], m_);
        float al = __expf(mr[sub][r] - mnew);
        float ls = 0.f;
        int prow = (quad * 4 + r) * 136;
#pragma unroll
        for (int nt = 0; nt < 8; ++nt) {
          float p = __expf(sf[sub][nt][r] - mnew);
          ls += p;
          sPw[prow + nt * 16 + l16] = f2b(p);
        }
#pragma unroll
        for (int off = 1; off < 16; off <<= 1) ls += __shfl_xor(ls, off);
        lr[sub][r] = lr[sub][r] * al + ls;
        mr[sub][r] = mnew;
#pragma unroll
        for (int nc = 0; nc < 4; ++nc) on[sub][nc][r] *= al;
      }
      // PV for this subtile (P is wave-private; same-wave LDS ordering via lgkmcnt)
#pragma unroll
      for (int ks = 0; ks < 4; ++ks) {
        short8 pf = *reinterpret_cast<const short8*>(sPw + l16 * 136 + ks * 32 + quad * 8);
#pragma unroll
        for (int nc = 0; nc < 4; ++nc) {
          short8 vf = *reinterpret_cast<const short8*>(sV + (nc * 16 + l16) * 136 + ks * 32 + quad * 8);
          on[sub][nc] = __builtin_amdgcn_mfma_f32_16x16x32_bf16(pf, vf, on[sub][nc], 0, 0, 0);
        }
      }
    }
  }
  // ---- finalize: normalize, bounce via wave-private sP for coalesced writes
#pragma unroll
  for (int sub = 0; sub < 2; ++sub) {
#pragma unroll
    for (int r = 0; r < 4; ++r) {
      float inv = 1.f / lr[sub][r];
      int prow = (quad * 4 + r) * 136;
#pragma unroll
      for (int nc = 0; nc < 4; ++nc)
        sPw[prow + nc * 16 + l16] = f2b(on[sub][nc][r] * inv);
    }
    int row = lane >> 2, cpart = (lane & 3) * 16;
    uint4 o0 = *reinterpret_cast<const uint4*>(sPw + row * 136 + cpart);
    uint4 o1 = *reinterpret_cast<const uint4*>(sPw + row * 136 + cpart + 8);
    ushort_t* obase = Ot + (size_t)(nq0 + sub * 64 + wave * 16 + row) * 768 + hc + cpart;
    *reinterpret_cast<uint4*>(obase) = o0;
    *reinterpret_cast<uint4*>(obase + 8) = o1;
  }
}

// ---------------------------------------------------------------------------
extern "C" void kernel_launch(void* const* d_in, const int* in_sizes, int n_in,
                              void* d_out, int out_size, void* d_ws, size_t ws_size,
                              hipStream_t stream) {
  (void)in_sizes; (void)n_in; (void)out_size; (void)ws_size;
  const float* video = (const float*)d_in[0];
  const float* audio = (const float*)d_in[1];
  const float* vn_s = (const float*)d_in[2];
  const float* vn_b = (const float*)d_in[3];
  const float* an_s = (const float*)d_in[4];
  const float* an_b = (const float*)d_in[5];
  const float* vqkv_w = (const float*)d_in[6];
  const float* vqkv_b = (const float*)d_in[7];
  const float* aqkv_w = (const float*)d_in[8];
  const float* aqkv_b = (const float*)d_in[9];
  const float* vproj_w = (const float*)d_in[10];
  const float* vproj_b = (const float*)d_in[11];
  const float* aproj_w = (const float*)d_in[12];
  const float* aproj_b = (const float*)d_in[13];

  float* out_v = (float*)d_out;
  float* out_a = out_v + (size_t)4 * 16 * 768 * 16 * 16;

  char* ws = (char*)d_ws;
  size_t off = 0;
  auto carve = [&](size_t bytes) {
    char* p = ws + off;
    off += (bytes + 255) & ~(size_t)255;
    return p;
  };
  float* mu = (float*)carve(256 * 4);
  float* rs = (float*)carve(256 * 4);
  float* part = (float*)carve(2560 * 2 * 4);
  ushort_t* Xv = (ushort_t*)carve((size_t)16384 * 768 * 2);
  ushort_t* Xa = (ushort_t*)carve((size_t)4096 * 768 * 2);
  ushort_t* Wqv = (ushort_t*)carve((size_t)2304 * 768 * 2);
  ushort_t* Wqa = (ushort_t*)carve((size_t)2304 * 768 * 2);
  ushort_t* Wpv = (ushort_t*)carve((size_t)768 * 768 * 2);
  ushort_t* Wpa = (ushort_t*)carve((size_t)768 * 768 * 2);
  ushort_t* Qv = (ushort_t*)carve((size_t)16384 * 768 * 2);
  ushort_t* Kv = (ushort_t*)carve((size_t)16384 * 768 * 2);
  ushort_t* Vv = (ushort_t*)carve((size_t)16384 * 768 * 2);
  ushort_t* Qa = (ushort_t*)carve((size_t)4096 * 768 * 2);
  ushort_t* Ka = (ushort_t*)carve((size_t)4096 * 768 * 2);
  ushort_t* Va = (ushort_t*)carve((size_t)4096 * 768 * 2);
  ushort_t* Ov = Xv;  // alias: X no longer needed after QKV GEMM
  ushort_t* Oa = Xa;

  wcvt_kernel<<<1024, 256, 0, stream>>>(vqkv_w, aqkv_w, vproj_w, aproj_w, Wqv, Wqa, Wpv, Wpa);
  gn_partial_kernel<<<2560, 256, 0, stream>>>(video, audio, part);
  gn_final_kernel<<<1, 256, 0, stream>>>(part, mu, rs);
  norm_video_kernel<<<1536, 256, 0, stream>>>(video, mu, rs, vn_s, vn_b, Xv);
  norm_audio_kernel<<<384, 256, 0, stream>>>(audio, mu, rs, an_s, an_b, Xa);
  gemm_kernel<0><<<dim3(18, 128), 256, 0, stream>>>(Xv, Wqv, vqkv_b, Qv, Kv, Vv, 16384);
  gemm_kernel<0><<<dim3(18, 32), 256, 0, stream>>>(Xa, Wqa, aqkv_b, Qa, Ka, Va, 4096);
  // video queries attend audio windows: QW=1024, SW=256
  attn_mfma3_kernel<1024, 256><<<1536, 256, 0, stream>>>(Qv, Ka, Va, Ov, 4096, 1024, 4096);
  // audio queries attend video windows: QW=256, SW=1024
  attn_mfma3_kernel<256, 1024><<<384, 256, 0, stream>>>(Qa, Kv, Vv, Oa, 1024, 4096, 16384);
  gemm_kernel<1><<<dim3(6, 128), 256, 0, stream>>>(Ov, Wpv, vproj_b, (void*)out_v, (void*)video, nullptr, 16384);
  gemm_kernel<2><<<dim3(6, 32), 256, 0, stream>>>(Oa, Wpa, aproj_b, (void*)out_a, (void*)audio, nullptr, 4096);
}